// Round 1
// baseline (844.935 us; speedup 1.0000x reference)
//
#include <hip/hip_runtime.h>

typedef __bf16 v8bf __attribute__((ext_vector_type(8)));
typedef float  v4f  __attribute__((ext_vector_type(4)));

#define MFMA16x16x32 __builtin_amdgcn_mfma_f32_16x16x32_bf16

#define HIDDEN 128
#define NHEADS 8

// ---------------- K1: q = x @ Wq + bq  (bf16 MFMA, Wq frags in regs) ----------------
__global__ __launch_bounds__(512) void q_kernel(const float* __restrict__ x,
    const float* __restrict__ Wq, const float* __restrict__ bq,
    float* __restrict__ q, int N)
{
  __shared__ __bf16 X[32][136];   // 32 nodes x 128 (+8 pad), k-contiguous
  const int tid = threadIdx.x;
  const int w = tid >> 6, l = tid & 63, qd = l >> 4, ln = l & 15;
  const int col = w*16 + ln;      // wave w owns output cols [w*16, w*16+16)

  // persistent B fragments: B[k][n], lane holds n=col, k = kk*32 + qd*8 + j
  v8bf B[4];
  #pragma unroll
  for (int kk=0; kk<4; kk++) {
    v8bf f;
    #pragma unroll
    for (int j=0;j<8;j++) f[j] = (__bf16)Wq[(kk*32 + qd*8 + j)*HIDDEN + col];
    B[kk] = f;
  }
  const float bqv = bq[col];

  const int s = tid >> 4, c8 = (tid & 15)*8;
  for (int n0 = blockIdx.x*32; n0 < N; n0 += gridDim.x*32) {
    __syncthreads();
    int n = n0 + s;
    v8bf xv;
    if (n < N) {
      const float4* xp = (const float4*)(x + (long)n*HIDDEN + c8);
      float4 a = xp[0], b = xp[1];
      xv[0]=(__bf16)a.x; xv[1]=(__bf16)a.y; xv[2]=(__bf16)a.z; xv[3]=(__bf16)a.w;
      xv[4]=(__bf16)b.x; xv[5]=(__bf16)b.y; xv[6]=(__bf16)b.z; xv[7]=(__bf16)b.w;
    } else {
      #pragma unroll
      for (int j=0;j<8;j++) xv[j] = (__bf16)0.f;
    }
    *(v8bf*)&X[s][c8] = xv;
    __syncthreads();

    v4f acc0 = {0.f,0.f,0.f,0.f}, acc1 = {0.f,0.f,0.f,0.f};
    #pragma unroll
    for (int kk=0;kk<4;kk++) {
      v8bf a0 = *(const v8bf*)&X[ln][kk*32 + qd*8];
      v8bf a1 = *(const v8bf*)&X[16+ln][kk*32 + qd*8];
      acc0 = MFMA16x16x32(a0, B[kk], acc0, 0,0,0);
      acc1 = MFMA16x16x32(a1, B[kk], acc1, 0,0,0);
    }
    // C/D layout: col = lane&15 (n), row = quad*4 + reg (m)
    #pragma unroll
    for (int r=0;r<4;r++) {
      int n_o = n0 + qd*4 + r;
      if (n_o < N) q[(long)n_o*HIDDEN + col] = acc0[r] + bqv;
      int n_o2 = n0 + 16 + qd*4 + r;
      if (n_o2 < N) q[(long)n_o2*HIDDEN + col] = acc1[r] + bqv;
    }
  }
}

// ---------------- K2: main fused edge kernel ----------------
__global__ __launch_bounds__(512) void edge_kernel(
    const float* __restrict__ x, const float* __restrict__ ts,
    const int* __restrict__ src, const int* __restrict__ dst,
    const int* __restrict__ etyp, const float* __restrict__ etime,
    const float* __restrict__ rel,
    const float* __restrict__ Wk, const float* __restrict__ bk,
    const float* __restrict__ Wv, const float* __restrict__ bv,
    const float* __restrict__ W1, const float* __restrict__ b1,
    const float* __restrict__ W2, const float* __restrict__ b2,
    const float* __restrict__ tc,
    const float* __restrict__ qws, float* __restrict__ denom,
    float* __restrict__ out, int E)
{
  __shared__ __bf16 A[32][264];    // [src_emb(128) | rel_emb(128)] + 8 pad
  __shared__ __bf16 A2[32][136];   // message
  __shared__ float sW2[128], sb1[128], sw1r[128], sbk[128], sbv[128];
  __shared__ float stm[32], sdw[32];
  __shared__ int   ssrc[32], sdst[32], styp[32];
  __shared__ float dwpart[8][32];

  const int tid = threadIdx.x;
  const int w = tid >> 6, l = tid & 63, qd = l >> 4, ln = l & 15;
  const int col = w*16 + ln;        // wave w owns cols [w*16, w*16+16) == head w

  // persistent B fragments for W1 (K=256), Wk, Wv (K=128): loaded once per block
  v8bf B1[8], BK[4], BV[4];
  #pragma unroll
  for (int kk=0;kk<8;kk++){ v8bf f;
    #pragma unroll
    for (int j=0;j<8;j++) f[j] = (__bf16)W1[(kk*32+qd*8+j)*HIDDEN + col];
    B1[kk]=f; }
  #pragma unroll
  for (int kk=0;kk<4;kk++){ v8bf f,g;
    #pragma unroll
    for (int j=0;j<8;j++){ f[j] = (__bf16)Wk[(kk*32+qd*8+j)*HIDDEN + col];
                           g[j] = (__bf16)Wv[(kk*32+qd*8+j)*HIDDEN + col]; }
    BK[kk]=f; BV[kk]=g; }

  if (tid < 128) {
    sW2[tid]  = W2[tid];
    sb1[tid]  = b1[tid];
    sw1r[tid] = W1[256*HIDDEN + tid];  // W1 row 256 (time_mask input)
    sbk[tid]  = bk[tid];
    sbv[tid]  = bv[tid];
  }
  const float b2v = b2[0];
  const float invtc = 1.0f / (fabsf(tc[0]) + 1e-9f);

  const int s = tid >> 4, c8 = (tid & 15)*8;
  const int ntiles = (E + 31) >> 5;
  for (int t = blockIdx.x; t < ntiles; t += gridDim.x) {
    const int e0 = t*32;
    __syncthreads();   // protect LDS reuse across tiles (and initial stores above)
    if (tid < 32) {
      int e = e0 + tid;
      if (e < E) {
        int d = dst[e];
        ssrc[tid] = src[e]; sdst[tid] = d; styp[tid] = etyp[e];
        float dt = (ts[d] - etime[e]) * invtc;
        stm[tid] = 1.0f / (1.0f + expf(-dt));
      } else { ssrc[tid]=0; sdst[tid]=0; styp[tid]=0; stm[tid]=0.f; }
    }
    __syncthreads();

    // ---- stage A tile: thread = (edge s, chunk c8) ----
    {
      const float tmv = stm[s];
      const float4* xp = (const float4*)(x + (long)ssrc[s]*HIDDEN + c8);
      float4 a = xp[0], b = xp[1];
      const float4* rp = (const float4*)(rel + (long)styp[s]*HIDDEN + c8);
      float4 ra = rp[0], rb = rp[1];
      v8bf sv, rv;
      sv[0]=(__bf16)a.x; sv[1]=(__bf16)a.y; sv[2]=(__bf16)a.z; sv[3]=(__bf16)a.w;
      sv[4]=(__bf16)b.x; sv[5]=(__bf16)b.y; sv[6]=(__bf16)b.z; sv[7]=(__bf16)b.w;
      rv[0]=(__bf16)(ra.x*tmv); rv[1]=(__bf16)(ra.y*tmv);
      rv[2]=(__bf16)(ra.z*tmv); rv[3]=(__bf16)(ra.w*tmv);
      rv[4]=(__bf16)(rb.x*tmv); rv[5]=(__bf16)(rb.y*tmv);
      rv[6]=(__bf16)(rb.z*tmv); rv[7]=(__bf16)(rb.w*tmv);
      *(v8bf*)&A[s][c8] = sv;
      *(v8bf*)&A[s][128 + c8] = rv;
    }
    __syncthreads();

    // ---- GEMM1: H = A[32,256] @ W1[0:256,:]  ----
    v4f acc0 = {0.f,0.f,0.f,0.f}, acc1 = {0.f,0.f,0.f,0.f};
    #pragma unroll
    for (int kk=0;kk<8;kk++){
      v8bf a0 = *(const v8bf*)&A[ln][kk*32 + qd*8];
      v8bf a1 = *(const v8bf*)&A[16+ln][kk*32 + qd*8];
      acc0 = MFMA16x16x32(a0, B1[kk], acc0, 0,0,0);
      acc1 = MFMA16x16x32(a1, B1[kk], acc1, 0,0,0);
    }
    // ---- h = relu(pre + tm*W1[256] + b1); partial dot h.W2 ----
    float part[8];
    {
      const float w1rj = sw1r[col], b1j = sb1[col], w2j = sW2[col];
      #pragma unroll
      for (int r=0;r<4;r++){
        int i0 = qd*4 + r, i1 = 16 + qd*4 + r;
        float p0 = acc0[r] + stm[i0]*w1rj + b1j;
        float p1 = acc1[r] + stm[i1]*w1rj + b1j;
        part[r]   = fmaxf(p0, 0.f)*w2j;
        part[4+r] = fmaxf(p1, 0.f)*w2j;
      }
    }
    #pragma unroll
    for (int m=1;m<16;m<<=1){
      #pragma unroll
      for (int i=0;i<8;i++) part[i] += __shfl_xor(part[i], m, 16);
    }
    if (ln == 0){
      #pragma unroll
      for (int r=0;r<4;r++){ dwpart[w][qd*4+r] = part[r]; dwpart[w][16+qd*4+r] = part[4+r]; }
    }
    __syncthreads();
    if (tid < 32){
      float z = b2v;
      #pragma unroll
      for (int ww=0;ww<8;ww++) z += dwpart[ww][tid];
      sdw[tid] = 1.0f / (1.0f + expf(-z));
    }
    __syncthreads();

    // ---- message = src_emb * rel_emb * dw ----
    {
      const float dwv = sdw[s];
      v8bf mv;
      #pragma unroll
      for (int i=0;i<8;i++){
        float svv = (float)A[s][c8+i];
        float rvv = (float)A[s][128+c8+i];
        mv[i] = (__bf16)(svv*rvv*dwv);
      }
      *(v8bf*)&A2[s][c8] = mv;
    }
    __syncthreads();

    // ---- GEMM2/3: k = msg@Wk, v = msg@Wv ----
    v4f k0={0.f,0.f,0.f,0.f}, k1={0.f,0.f,0.f,0.f};
    v4f v0={0.f,0.f,0.f,0.f}, v1={0.f,0.f,0.f,0.f};
    #pragma unroll
    for (int kk=0;kk<4;kk++){
      v8bf a0 = *(const v8bf*)&A2[ln][kk*32 + qd*8];
      v8bf a1 = *(const v8bf*)&A2[16+ln][kk*32 + qd*8];
      k0 = MFMA16x16x32(a0, BK[kk], k0, 0,0,0);
      k1 = MFMA16x16x32(a1, BK[kk], k1, 0,0,0);
      v0 = MFMA16x16x32(a0, BV[kk], v0, 0,0,0);
      v1 = MFMA16x16x32(a1, BV[kk], v1, 0,0,0);
    }

    // ---- scores: head w = cols [w*16, w*16+16); reduce over 16 lanes ----
    float sc[8];
    const float bkj = sbk[col], bvj = sbv[col];
    #pragma unroll
    for (int r=0;r<4;r++){
      int i0 = qd*4 + r, i1 = 16 + qd*4 + r;
      float kv0 = k0[r] + bkj, kv1 = k1[r] + bkj;
      float q0 = qws[(long)sdst[i0]*HIDDEN + col];
      float q1 = qws[(long)sdst[i1]*HIDDEN + col];
      sc[r] = kv0*q0; sc[4+r] = kv1*q1;
    }
    #pragma unroll
    for (int m=1;m<16;m<<=1){
      #pragma unroll
      for (int i=0;i<8;i++) sc[i] += __shfl_xor(sc[i], m, 16);
    }
    float ee[8];
    #pragma unroll
    for (int i=0;i<8;i++) ee[i] = expf(sc[i]*0.25f);   // / sqrt(16)

    if (ln == 0){
      #pragma unroll
      for (int r=0;r<4;r++){
        int i0 = qd*4 + r, i1 = 16 + qd*4 + r;
        if (e0+i0 < E) atomicAdd(&denom[(long)sdst[i0]*NHEADS + w], ee[r]);
        if (e0+i1 < E) atomicAdd(&denom[(long)sdst[i1]*NHEADS + w], ee[4+r]);
      }
    }
    #pragma unroll
    for (int r=0;r<4;r++){
      int i0 = qd*4 + r, i1 = 16 + qd*4 + r;
      if (e0+i0 < E) atomicAdd(&out[(long)sdst[i0]*HIDDEN + col], ee[r]*(v0[r]+bvj));
      if (e0+i1 < E) atomicAdd(&out[(long)sdst[i1]*HIDDEN + col], ee[4+r]*(v1[r]+bvj));
    }
  }
}

// ---------------- K3: out /= denom ----------------
__global__ void fin_kernel(float* __restrict__ out, const float* __restrict__ denom, int N)
{
  int idx = blockIdx.x*blockDim.x + threadIdx.x;   // one float4 each
  int total = N*32;
  if (idx < total){
    int n = idx >> 5;
    int j4 = idx & 31;
    int h = j4 >> 2;           // 4 float4s per head
    float d = denom[n*8 + h];
    float inv = d > 0.f ? 1.0f/d : 0.f;
    float4* p = (float4*)out + idx;
    float4 v = *p;
    v.x*=inv; v.y*=inv; v.z*=inv; v.w*=inv;
    *p = v;
  }
}

extern "C" void kernel_launch(void* const* d_in, const int* in_sizes, int n_in,
                              void* d_out, int out_size, void* d_ws, size_t ws_size,
                              hipStream_t stream)
{
  const float* x      = (const float*)d_in[0];
  const float* ts     = (const float*)d_in[1];
  const int*   src    = (const int*)d_in[2];
  const int*   dstp   = (const int*)d_in[3];
  const int*   etyp   = (const int*)d_in[4];
  const float* etime  = (const float*)d_in[5];
  const float* rel    = (const float*)d_in[6];
  const float* Wq     = (const float*)d_in[7];
  const float* bq     = (const float*)d_in[8];
  const float* Wk     = (const float*)d_in[9];
  const float* bk     = (const float*)d_in[10];
  const float* Wv     = (const float*)d_in[11];
  const float* bv     = (const float*)d_in[12];
  const float* W1     = (const float*)d_in[13];
  const float* b1     = (const float*)d_in[14];
  const float* W2     = (const float*)d_in[15];
  const float* b2     = (const float*)d_in[16];
  const float* tc     = (const float*)d_in[17];
  float* out = (float*)d_out;

  const int N = in_sizes[0] / HIDDEN;
  const int E = in_sizes[2];

  float* qws   = (float*)d_ws;                 // [N,128] f32
  float* denom = qws + (size_t)N*HIDDEN;       // [N,8]  f32

  hipMemsetAsync(out,   0, (size_t)N*HIDDEN*sizeof(float), stream);
  hipMemsetAsync(denom, 0, (size_t)N*NHEADS*sizeof(float), stream);

  q_kernel<<<512, 512, 0, stream>>>(x, Wq, bq, qws, N);
  edge_kernel<<<512, 512, 0, stream>>>(x, ts, src, dstp, etyp, etime, rel,
      Wk, bk, Wv, bv, W1, b1, W2, b2, tc, qws, denom, out, E);
  fin_kernel<<<(N*32 + 255)/256, 256, 0, stream>>>(out, denom, N);
}